// Round 1
// baseline (605.699 us; speedup 1.0000x reference)
//
#include <hip/hip_runtime.h>
#include <hip/hip_bf16.h>
#include <math.h>

// ---------------- sizes ----------------
#define BATCH 128
#define SEQ   2048
#define FIN   128
#define DD    16
#define NLAYERS 6

// ws layout (floats)
#define BUFA_F  (BATCH*SEQ*DD)            // 4,194,304
#define BUFB_F  (BATCH*(SEQ/2)*DD)        // 2,097,152
#define U1_OFF  (BUFA_F + BUFB_F)
#define U2_OFF  (U1_OFF + NLAYERS*4096)
#define WT_OFF  (U2_OFF + NLAYERS*4096)

// ---------------- prep: u1 = mean_l u, u2 = mean_k u, wt = w transposed ----------------
__global__ __launch_bounds__(256) void k_prep(const float* __restrict__ u,
                                              const float* __restrict__ w,
                                              float* __restrict__ u1,
                                              float* __restrict__ u2,
                                              float* __restrict__ wt) {
    int l  = blockIdx.x;        // 0..5
    int ij = threadIdx.x;       // 0..255  (= i*16+j)
    const float* ub = u + (size_t)l*65536 + (size_t)ij*256;   // [k][l2]
    float a1[16], a2[16];
#pragma unroll
    for (int k = 0; k < 16; ++k) { a1[k] = 0.0f; a2[k] = 0.0f; }
#pragma unroll
    for (int k = 0; k < 16; ++k) {
#pragma unroll
        for (int z = 0; z < 16; ++z) {
            float v = ub[k*16 + z];
            a1[k] += v;
            a2[z] += v;
        }
    }
    float* u1p = u1 + (size_t)l*4096 + ij*16;
    float* u2p = u2 + (size_t)l*4096 + ij*16;
#pragma unroll
    for (int k = 0; k < 16; ++k) { u1p[k] = a1[k]*(1.0f/16.0f); u2p[k] = a2[k]*(1.0f/16.0f); }

    const float* wb = w + (size_t)l*4096;      // [a][i][j]
    float* wtp = wt + (size_t)l*4096 + ij*16;  // [i][j][a]
#pragma unroll
    for (int a = 0; a < 16; ++a) wtp[a] = wb[a*256 + ij];
}

// ---------------- embedding + normalize ----------------
#define EROWS 32
__global__ __launch_bounds__(256) void k_embed(const float* __restrict__ seq,
                                               const float* __restrict__ W,
                                               const float* __restrict__ bias,
                                               float* __restrict__ out) {
    __shared__ float4 rl[EROWS*33];     // 32 rows x 128 floats, padded (33 float4/row)
    __shared__ float  wt[16*132];       // transposed W, padded rows of 132
    __shared__ float  bl[16];
    int t = threadIdx.x;
    for (int x = t; x < 2048; x += 256) {
        int k = x >> 4, d = x & 15;
        wt[d*132 + k] = W[x];
    }
    if (t < 16) bl[t] = bias[t];
    size_t rowbase = (size_t)blockIdx.x * EROWS;
    const float4* seq4 = (const float4*)seq + rowbase*32;
    for (int x = t; x < EROWS*32; x += 256) rl[(x >> 5)*33 + (x & 31)] = seq4[x];
    __syncthreads();

    int r  = t >> 3;     // row in tile 0..31
    int g  = t & 7;      // dim group
    int d0 = g*2;
    float a0 = bl[d0], a1 = bl[d0+1];
    const float4* wA = (const float4*)(wt + d0*132);
    const float4* wB = (const float4*)(wt + (d0+1)*132);
#pragma unroll
    for (int kk = 0; kk < 32; ++kk) {
        float4 rv = rl[r*33 + kk];
        float4 wa = wA[kk], wb = wB[kk];
        a0 = fmaf(rv.x, wa.x, a0); a0 = fmaf(rv.y, wa.y, a0);
        a0 = fmaf(rv.z, wa.z, a0); a0 = fmaf(rv.w, wa.w, a0);
        a1 = fmaf(rv.x, wb.x, a1); a1 = fmaf(rv.y, wb.y, a1);
        a1 = fmaf(rv.z, wb.z, a1); a1 = fmaf(rv.w, wb.w, a1);
    }
    float p = a0*a0 + a1*a1;
    p += __shfl_xor(p, 1); p += __shfl_xor(p, 2); p += __shfl_xor(p, 4);
    float inv = 1.0f / fmaxf(sqrtf(p), 1e-12f);
    float2 o; o.x = a0*inv; o.y = a1*inv;
    ((float2*)(out + (rowbase + r)*16))[g] = o;
}

// ---------------- one MERA layer ----------------
__global__ __launch_bounds__(256) void k_layer(const float* __restrict__ in,
                                               float* __restrict__ outp,
                                               const float* __restrict__ u1,
                                               const float* __restrict__ u2,
                                               const float* __restrict__ wtm) {
    __shared__ float s0l[16*256];
    __shared__ float o1l[16*256];
    int t = threadIdx.x;
    size_t gidx = (size_t)blockIdx.x*256 + t;     // pair index; rows 2g,2g+1 -> row g
    const float4* ip = (const float4*)(in + gidx*32);
    float4 A0 = ip[0], A1 = ip[1], A2 = ip[2], A3 = ip[3];   // s0
    float4 B0 = ip[4], B1 = ip[5], B2 = ip[6], B3 = ip[7];   // s1
    float s1v[16];
    s1v[0]=B0.x; s1v[1]=B0.y; s1v[2]=B0.z; s1v[3]=B0.w;
    s1v[4]=B1.x; s1v[5]=B1.y; s1v[6]=B1.z; s1v[7]=B1.w;
    s1v[8]=B2.x; s1v[9]=B2.y; s1v[10]=B2.z; s1v[11]=B2.w;
    s1v[12]=B3.x; s1v[13]=B3.y; s1v[14]=B3.z; s1v[15]=B3.w;
    s0l[0*256+t]=A0.x;  s0l[1*256+t]=A0.y;  s0l[2*256+t]=A0.z;  s0l[3*256+t]=A0.w;
    s0l[4*256+t]=A1.x;  s0l[5*256+t]=A1.y;  s0l[6*256+t]=A1.z;  s0l[7*256+t]=A1.w;
    s0l[8*256+t]=A2.x;  s0l[9*256+t]=A2.y;  s0l[10*256+t]=A2.z; s0l[11*256+t]=A2.w;
    s0l[12*256+t]=A3.x; s0l[13*256+t]=A3.y; s0l[14*256+t]=A3.z; s0l[15*256+t]=A3.w;

    float o1[16], o2[16];
#pragma unroll
    for (int k = 0; k < 16; ++k) { o1[k] = 0.0f; o2[k] = 0.0f; }

    for (int i = 0; i < 16; ++i) {               // rolled; uniform u addresses
        float s0i = s0l[i*256 + t];
        const float* U1 = u1 + i*256;
        const float* U2 = u2 + i*256;
#pragma unroll
        for (int j = 0; j < 16; ++j) {
            float pij = s0i * s1v[j];
#pragma unroll
            for (int k = 0; k < 16; ++k) {
                o1[k] = fmaf(pij, U1[j*16+k], o1[k]);
                o2[k] = fmaf(pij, U2[j*16+k], o2[k]);
            }
        }
    }
#pragma unroll
    for (int k = 0; k < 16; ++k) o1l[k*256+t] = o1[k];

    float acc[16];
#pragma unroll
    for (int k = 0; k < 16; ++k) acc[k] = 0.0f;
    for (int i = 0; i < 16; ++i) {
        float o1i = o1l[i*256 + t];
        const float* WT = wtm + i*256;
#pragma unroll
        for (int j = 0; j < 16; ++j) {
            float qij = o1i * o2[j];
#pragma unroll
            for (int k = 0; k < 16; ++k) acc[k] = fmaf(qij, WT[j*16+k], acc[k]);
        }
    }
    float4* op = (float4*)(outp + gidx*16);
    op[0] = make_float4(acc[0],acc[1],acc[2],acc[3]);
    op[1] = make_float4(acc[4],acc[5],acc[6],acc[7]);
    op[2] = make_float4(acc[8],acc[9],acc[10],acc[11]);
    op[3] = make_float4(acc[12],acc[13],acc[14],acc[15]);
}

// ---------------- phi_q: corr + one-sided Jacobi SVD + entropies ----------------
__device__ __forceinline__ void rot_cs(float al, float be, float ga, float& c, float& s) {
    float ze = (be - al) / (2.0f * ga);
    float tt = copysignf(1.0f, ze) / (fabsf(ze) + sqrtf(1.0f + ze*ze));
    c = 1.0f / sqrtf(1.0f + tt*tt);
    s = c * tt;
}

__global__ __launch_bounds__(64) void k_phi(const float* __restrict__ sites,
                                            float* __restrict__ phi) {
    __shared__ float S[32*16];
    __shared__ float C16[256];     // col-major [col*16+row]
    __shared__ float C8[2][64];    // col-major [col*8+row]
    __shared__ float sv[32];
    __shared__ float ents[3];
    int b = blockIdx.x, t = threadIdx.x;
    const float* sp = sites + (size_t)b*512;
    for (int x = t; x < 512; x += 64) S[x] = sp[x];
    __syncthreads();

    for (int e = t; e < 384; e += 64) {
        int ra, rb; float* dst;
        if (e < 256)      { int i=e&15, j=e>>4;          ra=i;    rb=16+j; dst=&C16[j*16+i]; }
        else if (e < 320) { int e2=e-256; int i=e2&7, j=e2>>3; ra=i;    rb=8+j;  dst=&C8[0][j*8+i]; }
        else              { int e2=e-320; int i=e2&7, j=e2>>3; ra=16+i; rb=24+j; dst=&C8[1][j*8+i]; }
        float acc = 0.0f;
        for (int k = 0; k < 16; ++k) acc = fmaf(S[ra*16+k], S[rb*16+k], acc);
        *dst = acc;
    }
    __syncthreads();

    // 16x16: 8 pairs x 8 lanes (2 rows/lane)
    for (int sw = 0; sw < 12; ++sw) {
        for (int r = 0; r < 15; ++r) {
            int pr = t >> 3, sub = t & 7;
            int p, q;
            if (pr == 0) { p = 15; q = r; }
            else { p = (r + pr) % 15; q = (r + 15 - pr) % 15; }
            float u0 = C16[p*16 + 2*sub],   u1v = C16[p*16 + 2*sub + 1];
            float v0 = C16[q*16 + 2*sub],   v1v = C16[q*16 + 2*sub + 1];
            float al = u0*u0 + u1v*u1v;
            float be = v0*v0 + v1v*v1v;
            float ga = u0*v0 + u1v*v1v;
            al += __shfl_xor(al,1); al += __shfl_xor(al,2); al += __shfl_xor(al,4);
            be += __shfl_xor(be,1); be += __shfl_xor(be,2); be += __shfl_xor(be,4);
            ga += __shfl_xor(ga,1); ga += __shfl_xor(ga,2); ga += __shfl_xor(ga,4);
            if (ga != 0.0f) {
                float c, s; rot_cs(al, be, ga, c, s);
                C16[p*16 + 2*sub]     = fmaf(c, u0, -s*v0);
                C16[p*16 + 2*sub + 1] = fmaf(c, u1v, -s*v1v);
                C16[q*16 + 2*sub]     = fmaf(s, u0,  c*v0);
                C16[q*16 + 2*sub + 1] = fmaf(s, u1v, c*v1v);
            }
            __syncthreads();
        }
    }

    // two 8x8 in parallel: lanes [0,32) -> C8[0], [32,64) -> C8[1]; 4 pairs x 8 lanes
    for (int sw = 0; sw < 12; ++sw) {
        for (int r = 0; r < 7; ++r) {
            int mat = t >> 5, loc = t & 31, pr = loc >> 3, sub = loc & 7;
            float* C = C8[mat];
            int p, q;
            if (pr == 0) { p = 7; q = r; }
            else { p = (r + pr) % 7; q = (r + 7 - pr) % 7; }
            float uu = C[p*8 + sub], vv = C[q*8 + sub];
            float al = uu*uu, be = vv*vv, ga = uu*vv;
            al += __shfl_xor(al,1); al += __shfl_xor(al,2); al += __shfl_xor(al,4);
            be += __shfl_xor(be,1); be += __shfl_xor(be,2); be += __shfl_xor(be,4);
            ga += __shfl_xor(ga,1); ga += __shfl_xor(ga,2); ga += __shfl_xor(ga,4);
            if (ga != 0.0f) {
                float c, s; rot_cs(al, be, ga, c, s);
                C[p*8 + sub] = fmaf(c, uu, -s*vv);
                C[q*8 + sub] = fmaf(s, uu,  c*vv);
            }
            __syncthreads();
        }
    }

    // singular values = column norms
    if (t < 16) {
        float s2 = 0.0f;
        for (int rr = 0; rr < 16; ++rr) { float v = C16[t*16+rr]; s2 = fmaf(v, v, s2); }
        sv[t] = sqrtf(s2);
    } else if (t < 24) {
        int c = t - 16; float s2 = 0.0f;
        for (int rr = 0; rr < 8; ++rr) { float v = C8[0][c*8+rr]; s2 = fmaf(v, v, s2); }
        sv[t] = sqrtf(s2);
    } else if (t < 32) {
        int c = t - 24; float s2 = 0.0f;
        for (int rr = 0; rr < 8; ++rr) { float v = C8[1][c*8+rr]; s2 = fmaf(v, v, s2); }
        sv[t] = sqrtf(s2);
    }
    __syncthreads();

    if (t < 3) {
        const float* s0 = (t == 0) ? sv : (t == 1 ? sv + 16 : sv + 24);
        int n = (t == 0) ? 16 : 8;
        float sum = 0.0f;
        for (int i2 = 0; i2 < n; ++i2) sum += s0[i2];
        float den = sum + 1e-8f;
        float ent = 0.0f;
        for (int i2 = 0; i2 < n; ++i2) {
            float sn = s0[i2] / den;
            ent -= sn * logf(sn + 1e-8f);
        }
        ents[t] = ent;
    }
    __syncthreads();
    if (t == 0) phi[b] = fmaxf(ents[0] - (ents[1] + ents[2]), 0.0f);
}

// ---------------- launcher ----------------
extern "C" void kernel_launch(void* const* d_in, const int* in_sizes, int n_in,
                              void* d_out, int out_size, void* d_ws, size_t ws_size,
                              hipStream_t stream) {
    const float* seq  = (const float*)d_in[0];
    const float* W    = (const float*)d_in[1];
    const float* bias = (const float*)d_in[2];
    const float* u    = (const float*)d_in[3];
    const float* w    = (const float*)d_in[4];
    float* out = (float*)d_out;
    float* ws  = (float*)d_ws;

    float* bufA = ws;
    float* bufB = ws + BUFA_F;
    float* u1   = ws + U1_OFF;
    float* u2   = ws + U2_OFF;
    float* wt   = ws + WT_OFF;

    k_prep <<<NLAYERS, 256, 0, stream>>>(u, w, u1, u2, wt);
    k_embed<<<(BATCH*SEQ)/EROWS, 256, 0, stream>>>(seq, W, bias, bufA);

    const float* lin[6]  = { bufA, bufB, bufA, bufB, bufA, bufB };
    float*       lout[6] = { bufB, bufA, bufB, bufA, bufB, out  };
    int npairs = BATCH * (SEQ/2);
    for (int l = 0; l < NLAYERS; ++l) {
        k_layer<<<npairs/256, 256, 0, stream>>>(lin[l], lout[l],
                                                u1 + l*4096, u2 + l*4096, wt + l*4096);
        npairs >>= 1;
    }
    k_phi<<<BATCH, 64, 0, stream>>>(out, out + BATCH*32*DD);
}

// Round 2
// 281.600 us; speedup vs baseline: 2.1509x; 2.1509x over previous
//
#include <hip/hip_runtime.h>
#include <hip/hip_bf16.h>
#include <math.h>

// ---------------- sizes ----------------
#define BATCH 128
#define SEQ   2048
#define FIN   128
#define DD    16
#define NLAYERS 6

// ws layout (floats)
#define BUFA_F  (BATCH*SEQ*DD)            // 4,194,304
#define BUFB_F  (BATCH*(SEQ/2)*DD)        // 2,097,152
#define U1_OFF  (BUFA_F + BUFB_F)
#define U2_OFF  (U1_OFF + NLAYERS*4096)
#define WT_OFF  (U2_OFF + NLAYERS*4096)

// ---------------- prep: u1 = mean_l u, u2 = mean_k u, wt = w transposed ----------------
__global__ __launch_bounds__(256) void k_prep(const float* __restrict__ u,
                                              const float* __restrict__ w,
                                              float* __restrict__ u1,
                                              float* __restrict__ u2,
                                              float* __restrict__ wt) {
    int l  = blockIdx.x;        // 0..5
    int ij = threadIdx.x;       // 0..255  (= i*16+j)
    const float* ub = u + (size_t)l*65536 + (size_t)ij*256;   // [k][l2]
    float a1[16], a2[16];
#pragma unroll
    for (int k = 0; k < 16; ++k) { a1[k] = 0.0f; a2[k] = 0.0f; }
#pragma unroll
    for (int k = 0; k < 16; ++k) {
#pragma unroll
        for (int z = 0; z < 16; ++z) {
            float v = ub[k*16 + z];
            a1[k] += v;
            a2[z] += v;
        }
    }
    float* u1p = u1 + (size_t)l*4096 + ij*16;
    float* u2p = u2 + (size_t)l*4096 + ij*16;
#pragma unroll
    for (int k = 0; k < 16; ++k) { u1p[k] = a1[k]*(1.0f/16.0f); u2p[k] = a2[k]*(1.0f/16.0f); }

    const float* wb = w + (size_t)l*4096;      // [a][i][j]
    float* wtp = wt + (size_t)l*4096 + ij*16;  // [i][j][a]
#pragma unroll
    for (int a = 0; a < 16; ++a) wtp[a] = wb[a*256 + ij];
}

// ---------------- embedding + normalize ----------------
#define EROWS 32
__global__ __launch_bounds__(256) void k_embed(const float* __restrict__ seq,
                                               const float* __restrict__ W,
                                               const float* __restrict__ bias,
                                               float* __restrict__ out) {
    __shared__ float4 rl[EROWS*33];     // 32 rows x 128 floats, padded (33 float4/row)
    __shared__ float  wt[16*132];       // transposed W, padded rows of 132
    __shared__ float  bl[16];
    int t = threadIdx.x;
    for (int x = t; x < 2048; x += 256) {
        int k = x >> 4, d = x & 15;
        wt[d*132 + k] = W[x];
    }
    if (t < 16) bl[t] = bias[t];
    size_t rowbase = (size_t)blockIdx.x * EROWS;
    const float4* seq4 = (const float4*)seq + rowbase*32;
    for (int x = t; x < EROWS*32; x += 256) rl[(x >> 5)*33 + (x & 31)] = seq4[x];
    __syncthreads();

    int r  = t >> 3;     // row in tile 0..31
    int g  = t & 7;      // dim group
    int d0 = g*2;
    float a0 = bl[d0], a1 = bl[d0+1];
    const float4* wA = (const float4*)(wt + d0*132);
    const float4* wB = (const float4*)(wt + (d0+1)*132);
#pragma unroll
    for (int kk = 0; kk < 32; ++kk) {
        float4 rv = rl[r*33 + kk];
        float4 wa = wA[kk], wb = wB[kk];
        a0 = fmaf(rv.x, wa.x, a0); a0 = fmaf(rv.y, wa.y, a0);
        a0 = fmaf(rv.z, wa.z, a0); a0 = fmaf(rv.w, wa.w, a0);
        a1 = fmaf(rv.x, wb.x, a1); a1 = fmaf(rv.y, wb.y, a1);
        a1 = fmaf(rv.z, wb.z, a1); a1 = fmaf(rv.w, wb.w, a1);
    }
    float p = a0*a0 + a1*a1;
    p += __shfl_xor(p, 1); p += __shfl_xor(p, 2); p += __shfl_xor(p, 4);
    float inv = 1.0f / fmaxf(sqrtf(p), 1e-12f);
    float2 o; o.x = a0*inv; o.y = a1*inv;
    ((float2*)(out + (rowbase + r)*16))[g] = o;
}

// ---------------- one MERA layer: 4 lanes per pair, coeffs in LDS ----------------
// Layouts (floats): U1l/U2l/WTl[4096] flat ([i][j][k], k contiguous).
// sp[64 pairs][36]  (pair's 32 site floats, stride 36 to spread banks)
// o1l[64 pairs][20] (o1[16] per pair, stride 20)
__global__ __launch_bounds__(256) void k_layer(const float* __restrict__ in,
                                               float* __restrict__ outp,
                                               const float* __restrict__ u1g,
                                               const float* __restrict__ u2g,
                                               const float* __restrict__ wtg) {
    __shared__ float U1l[4096], U2l[4096], WTl[4096];
    __shared__ float sp[64*36];
    __shared__ float o1l[64*20];
    int t = threadIdx.x;

    // stage coefficients (coalesced)
    for (int x = t; x < 4096; x += 256) {
        U1l[x] = u1g[x];
        U2l[x] = u2g[x];
        WTl[x] = wtg[x];
    }
    // stage 64 pairs (2048 floats) of site data
    {
        const float4* ing = (const float4*)in + (size_t)blockIdx.x*512;
        float4 v0 = ing[t];
        float4 v1 = ing[t + 256];
        int p0 = t >> 3,        f0 = t & 7;
        int p1 = (t + 256) >> 3, f1 = (t + 256) & 7;
        *(float4*)&sp[p0*36 + f0*4] = v0;
        *(float4*)&sp[p1*36 + f1*4] = v1;
    }
    __syncthreads();

    int pl = t >> 2;        // pair within block 0..63
    int kg = t & 3;         // output k-group (4 outputs per lane)
    int wl = t & 63;        // lane in wave
    int wb = wl & ~3;       // pair base lane in wave

    // s1 (second site) into registers
    float s1[16];
#pragma unroll
    for (int g = 0; g < 4; ++g) {
        float4 v = *(const float4*)&sp[pl*36 + 16 + g*4];
        s1[g*4+0] = v.x; s1[g*4+1] = v.y; s1[g*4+2] = v.z; s1[g*4+3] = v.w;
    }

    const float4* U1f4 = (const float4*)U1l;
    const float4* U2f4 = (const float4*)U2l;
    const float4* WTf4 = (const float4*)WTl;

    float o1a[4] = {0,0,0,0}, o2a[4] = {0,0,0,0};
    for (int i = 0; i < 16; ++i) {
        float s0i = sp[pl*36 + i];
#pragma unroll
        for (int j = 0; j < 16; ++j) {
            float pij = s0i * s1[j];
            float4 c1 = U1f4[(i*16 + j)*4 + kg];
            float4 c2 = U2f4[(i*16 + j)*4 + kg];
            o1a[0] = fmaf(pij, c1.x, o1a[0]);
            o1a[1] = fmaf(pij, c1.y, o1a[1]);
            o1a[2] = fmaf(pij, c1.z, o1a[2]);
            o1a[3] = fmaf(pij, c1.w, o1a[3]);
            o2a[0] = fmaf(pij, c2.x, o2a[0]);
            o2a[1] = fmaf(pij, c2.y, o2a[1]);
            o2a[2] = fmaf(pij, c2.z, o2a[2]);
            o2a[3] = fmaf(pij, c2.w, o2a[3]);
        }
    }

    // o1 -> LDS (runtime-i access in phase 2); o2 -> full vector via shuffles
    *(float4*)&o1l[pl*20 + kg*4] = make_float4(o1a[0], o1a[1], o1a[2], o1a[3]);
    float o2f[16];
#pragma unroll
    for (int j = 0; j < 16; ++j)
        o2f[j] = __shfl(o2a[j & 3], wb + (j >> 2), 64);

    float acc[4] = {0,0,0,0};
    for (int i = 0; i < 16; ++i) {
        float o1i = o1l[pl*20 + i];
#pragma unroll
        for (int j = 0; j < 16; ++j) {
            float q = o1i * o2f[j];
            float4 cw = WTf4[(i*16 + j)*4 + kg];
            acc[0] = fmaf(q, cw.x, acc[0]);
            acc[1] = fmaf(q, cw.y, acc[1]);
            acc[2] = fmaf(q, cw.z, acc[2]);
            acc[3] = fmaf(q, cw.w, acc[3]);
        }
    }

    size_t gp = (size_t)blockIdx.x*64 + pl;
    *(float4*)(outp + gp*16 + kg*4) = make_float4(acc[0], acc[1], acc[2], acc[3]);
}

// ---------------- phi_q: corr + one-sided Jacobi SVD + entropies ----------------
__device__ __forceinline__ void rot_cs(float al, float be, float ga, float& c, float& s) {
    float ze = (be - al) / (2.0f * ga);
    float tt = copysignf(1.0f, ze) / (fabsf(ze) + sqrtf(1.0f + ze*ze));
    c = 1.0f / sqrtf(1.0f + tt*tt);
    s = c * tt;
}

__global__ __launch_bounds__(64) void k_phi(const float* __restrict__ sites,
                                            float* __restrict__ phi) {
    __shared__ float S[32*16];
    __shared__ float C16[256];     // col-major [col*16+row]
    __shared__ float C8[2][64];    // col-major [col*8+row]
    __shared__ float sv[32];
    __shared__ float ents[3];
    int b = blockIdx.x, t = threadIdx.x;
    const float* sp = sites + (size_t)b*512;
    for (int x = t; x < 512; x += 64) S[x] = sp[x];
    __syncthreads();

    for (int e = t; e < 384; e += 64) {
        int ra, rb; float* dst;
        if (e < 256)      { int i=e&15, j=e>>4;          ra=i;    rb=16+j; dst=&C16[j*16+i]; }
        else if (e < 320) { int e2=e-256; int i=e2&7, j=e2>>3; ra=i;    rb=8+j;  dst=&C8[0][j*8+i]; }
        else              { int e2=e-320; int i=e2&7, j=e2>>3; ra=16+i; rb=24+j; dst=&C8[1][j*8+i]; }
        float acc = 0.0f;
        for (int k = 0; k < 16; ++k) acc = fmaf(S[ra*16+k], S[rb*16+k], acc);
        *dst = acc;
    }
    __syncthreads();

    // 16x16: 8 pairs x 8 lanes (2 rows/lane)
    for (int sw = 0; sw < 12; ++sw) {
        for (int r = 0; r < 15; ++r) {
            int pr = t >> 3, sub = t & 7;
            int p, q;
            if (pr == 0) { p = 15; q = r; }
            else { p = (r + pr) % 15; q = (r + 15 - pr) % 15; }
            float u0 = C16[p*16 + 2*sub],   u1v = C16[p*16 + 2*sub + 1];
            float v0 = C16[q*16 + 2*sub],   v1v = C16[q*16 + 2*sub + 1];
            float al = u0*u0 + u1v*u1v;
            float be = v0*v0 + v1v*v1v;
            float ga = u0*v0 + u1v*v1v;
            al += __shfl_xor(al,1); al += __shfl_xor(al,2); al += __shfl_xor(al,4);
            be += __shfl_xor(be,1); be += __shfl_xor(be,2); be += __shfl_xor(be,4);
            ga += __shfl_xor(ga,1); ga += __shfl_xor(ga,2); ga += __shfl_xor(ga,4);
            if (ga != 0.0f) {
                float c, s; rot_cs(al, be, ga, c, s);
                C16[p*16 + 2*sub]     = fmaf(c, u0, -s*v0);
                C16[p*16 + 2*sub + 1] = fmaf(c, u1v, -s*v1v);
                C16[q*16 + 2*sub]     = fmaf(s, u0,  c*v0);
                C16[q*16 + 2*sub + 1] = fmaf(s, u1v, c*v1v);
            }
            __syncthreads();
        }
    }

    // two 8x8 in parallel: lanes [0,32) -> C8[0], [32,64) -> C8[1]; 4 pairs x 8 lanes
    for (int sw = 0; sw < 12; ++sw) {
        for (int r = 0; r < 7; ++r) {
            int mat = t >> 5, loc = t & 31, pr = loc >> 3, sub = loc & 7;
            float* C = C8[mat];
            int p, q;
            if (pr == 0) { p = 7; q = r; }
            else { p = (r + pr) % 7; q = (r + 7 - pr) % 7; }
            float uu = C[p*8 + sub], vv = C[q*8 + sub];
            float al = uu*uu, be = vv*vv, ga = uu*vv;
            al += __shfl_xor(al,1); al += __shfl_xor(al,2); al += __shfl_xor(al,4);
            be += __shfl_xor(be,1); be += __shfl_xor(be,2); be += __shfl_xor(be,4);
            ga += __shfl_xor(ga,1); ga += __shfl_xor(ga,2); ga += __shfl_xor(ga,4);
            if (ga != 0.0f) {
                float c, s; rot_cs(al, be, ga, c, s);
                C[p*8 + sub] = fmaf(c, uu, -s*vv);
                C[q*8 + sub] = fmaf(s, uu,  c*vv);
            }
            __syncthreads();
        }
    }

    // singular values = column norms
    if (t < 16) {
        float s2 = 0.0f;
        for (int rr = 0; rr < 16; ++rr) { float v = C16[t*16+rr]; s2 = fmaf(v, v, s2); }
        sv[t] = sqrtf(s2);
    } else if (t < 24) {
        int c = t - 16; float s2 = 0.0f;
        for (int rr = 0; rr < 8; ++rr) { float v = C8[0][c*8+rr]; s2 = fmaf(v, v, s2); }
        sv[t] = sqrtf(s2);
    } else if (t < 32) {
        int c = t - 24; float s2 = 0.0f;
        for (int rr = 0; rr < 8; ++rr) { float v = C8[1][c*8+rr]; s2 = fmaf(v, v, s2); }
        sv[t] = sqrtf(s2);
    }
    __syncthreads();

    if (t < 3) {
        const float* s0 = (t == 0) ? sv : (t == 1 ? sv + 16 : sv + 24);
        int n = (t == 0) ? 16 : 8;
        float sum = 0.0f;
        for (int i2 = 0; i2 < n; ++i2) sum += s0[i2];
        float den = sum + 1e-8f;
        float ent = 0.0f;
        for (int i2 = 0; i2 < n; ++i2) {
            float sn = s0[i2] / den;
            ent -= sn * logf(sn + 1e-8f);
        }
        ents[t] = ent;
    }
    __syncthreads();
    if (t == 0) phi[b] = fmaxf(ents[0] - (ents[1] + ents[2]), 0.0f);
}

// ---------------- launcher ----------------
extern "C" void kernel_launch(void* const* d_in, const int* in_sizes, int n_in,
                              void* d_out, int out_size, void* d_ws, size_t ws_size,
                              hipStream_t stream) {
    const float* seq  = (const float*)d_in[0];
    const float* W    = (const float*)d_in[1];
    const float* bias = (const float*)d_in[2];
    const float* u    = (const float*)d_in[3];
    const float* w    = (const float*)d_in[4];
    float* out = (float*)d_out;
    float* ws  = (float*)d_ws;

    float* bufA = ws;
    float* bufB = ws + BUFA_F;
    float* u1   = ws + U1_OFF;
    float* u2   = ws + U2_OFF;
    float* wt   = ws + WT_OFF;

    k_prep <<<NLAYERS, 256, 0, stream>>>(u, w, u1, u2, wt);
    k_embed<<<(BATCH*SEQ)/EROWS, 256, 0, stream>>>(seq, W, bias, bufA);

    const float* lin[6]  = { bufA, bufB, bufA, bufB, bufA, bufB };
    float*       lout[6] = { bufB, bufA, bufB, bufA, bufB, out  };
    int npairs = BATCH * (SEQ/2);
    for (int l = 0; l < NLAYERS; ++l) {
        k_layer<<<npairs/64, 256, 0, stream>>>(lin[l], lout[l],
                                               u1 + l*4096, u2 + l*4096, wt + l*4096);
        npairs >>= 1;
    }
    k_phi<<<BATCH, 64, 0, stream>>>(out, out + BATCH*32*DD);
}